// Round 13
// baseline (182.261 us; speedup 1.0000x reference)
//
#include <hip/hip_runtime.h>
#include <hip/hip_bf16.h>

#define NEXP 8
#define NEMB 1024
#define NTOK 8192
#define BM 256
#define BN 256
#define BK 64
#define NK  (NEMB / BK)   // 16 K-tiles of 64
#define MAXT 640
#define BLD_STRIPE 512

typedef __attribute__((ext_vector_type(8))) short  bf16x8;
typedef __attribute__((ext_vector_type(8))) unsigned short u16x8;
typedef __attribute__((ext_vector_type(4))) float  f32x4;

// ---- workspace layout (bytes) ----
#define XB_BYTES   (NTOK * NEMB * 2)
#define WB_BYTES   (NEXP * NEMB * NEMB * 2)
#define CNT_OFF    (XB_BYTES + WB_BYTES)
#define LTOK_OFF   (CNT_OFF + 256)
#define LWT_OFF    (LTOK_OFF + NEXP * NTOK * 4)
#define SELW_OFF   (LWT_OFF + NEXP * NTOK * 4)
#define META_OFF   (SELW_OFF + NTOK * 16)      // int meta[16 + MAXT]

__device__ __forceinline__ unsigned short f2bf(float f) {
    unsigned u = __builtin_bit_cast(unsigned, f);
    unsigned r = (u + 0x7fffu + ((u >> 16) & 1u)) >> 16;
    return (unsigned short)r;
}

// ---------------- fused: expert_w -> bf16 (blocks 0..4095) + gating (blocks 4096..6143) ----
__global__ __launch_bounds__(256)
void k_prep(const float* __restrict__ x, const float* __restrict__ gw,
            const float* __restrict__ ew, unsigned short* __restrict__ wb,
            unsigned short* __restrict__ xb, int4* __restrict__ selw) {
    if (blockIdx.x < 4096) {
        int i = (blockIdx.x * 256 + threadIdx.x) * 8;
        f32x4 v0 = *reinterpret_cast<const f32x4*>(ew + i);
        f32x4 v1 = *reinterpret_cast<const f32x4*>(ew + i + 4);
        u16x8 o;
#pragma unroll
        for (int j = 0; j < 4; ++j) { o[j] = f2bf(v0[j]); o[4 + j] = f2bf(v1[j]); }
        *reinterpret_cast<u16x8*>(wb + i) = o;
        return;
    }
    int t = threadIdx.x, wave = t >> 6, lane = t & 63;
    int n = (blockIdx.x - 4096) * 4 + wave;

    const float* xr = x + (size_t)n * NEMB + lane * 16;
    f32x4 xv[4];
#pragma unroll
    for (int j = 0; j < 4; ++j) xv[j] = *reinterpret_cast<const f32x4*>(xr + j * 4);

    u16x8 o0, o1;
#pragma unroll
    for (int q = 0; q < 4; ++q) {
        o0[q] = f2bf(xv[0][q]); o0[4 + q] = f2bf(xv[1][q]);
        o1[q] = f2bf(xv[2][q]); o1[4 + q] = f2bf(xv[3][q]);
    }
    u16x8* xo = reinterpret_cast<u16x8*>(xb + (size_t)n * NEMB + lane * 16);
    xo[0] = o0; xo[1] = o1;

    float p[NEXP];
#pragma unroll
    for (int e = 0; e < NEXP; ++e) {
        const float* gr = gw + e * NEMB + lane * 16;
        f32x4 a = xv[0] * *reinterpret_cast<const f32x4*>(gr);
#pragma unroll
        for (int j = 1; j < 4; ++j) a += xv[j] * *reinterpret_cast<const f32x4*>(gr + j * 4);
        p[e] = a[0] + a[1] + a[2] + a[3];
    }
#pragma unroll
    for (int e = 0; e < NEXP; ++e) {
        float v = p[e];
#pragma unroll
        for (int m = 1; m < 64; m <<= 1) v += __shfl_xor(v, m, 64);
        p[e] = v;
    }
    if (lane == 0) {
        int e0 = 0; float b0 = p[0];
#pragma unroll
        for (int e = 1; e < NEXP; ++e) if (p[e] > b0) { b0 = p[e]; e0 = e; }
        int e1 = -1; float b1 = -3.4e38f;
#pragma unroll
        for (int e = 0; e < NEXP; ++e) if (e != e0 && p[e] > b1) { b1 = p[e]; e1 = e; }
        float ex = __expf(b1 - b0);
        float inv = 1.f / (1.f + ex);
        int4 s;
        s.x = e0; s.y = e1;
        s.z = __float_as_int(inv); s.w = __float_as_int(ex * inv);
        selw[n] = s;
    }
}

// ---------------- build combined per-expert token list ----------------
__global__ __launch_bounds__(256)
void k_build(const int4* __restrict__ selw, int* __restrict__ counts,
             int* __restrict__ ltok, float* __restrict__ lwt) {
    int e = blockIdx.y;
    int n0 = blockIdx.x * BLD_STRIPE;
    __shared__ int lcnt, base;
    __shared__ int   toks[BLD_STRIPE];
    __shared__ float wts[BLD_STRIPE];
    if (threadIdx.x == 0) lcnt = 0;
    __syncthreads();
    for (int i = threadIdx.x; i < BLD_STRIPE; i += 256) {
        int4 s = selw[n0 + i];
        if (s.x == e) {
            int p = atomicAdd(&lcnt, 1);
            toks[p] = n0 + i; wts[p] = __int_as_float(s.z);
        }
        if (s.y == e) {
            int p = atomicAdd(&lcnt, 1);
            toks[p] = n0 + i; wts[p] = __int_as_float(s.w);
        }
    }
    __syncthreads();
    if (threadIdx.x == 0) base = atomicAdd(&counts[e], lcnt);
    __syncthreads();
    for (int i = threadIdx.x; i < lcnt; i += 256) {
        ltok[e * NTOK + base + i] = toks[i];
        lwt[e * NTOK + base + i]  = wts[i];
    }
}

// ---------------- pad lists + build K-split worklist ----------------
// entry = (e<<16) | (rb<<8) | (cb<<4) | kh   — e-major order for XCD chunking
__global__ void k_padW(const int* __restrict__ counts, int* __restrict__ ltok,
                       float* __restrict__ lwt, int* __restrict__ meta) {
    __shared__ int nt[NEXP], off[NEXP];
    int t = threadIdx.x;
    if (t < NEXP) nt[t] = (counts[t] + BM - 1) / BM;
    __syncthreads();
    if (t == 0) {
        int T = 0;
        for (int e = 0; e < NEXP; ++e) { off[e] = T; T += nt[e] * 8; }
        meta[0] = T;
    }
    __syncthreads();
    for (int e = 0; e < NEXP; ++e) {
        int ne = nt[e] * 8;                      // rb x 4cb x 2kh
        for (int j = t; j < ne; j += 256) {
            int rb = j >> 3, q = j & 7, cb = q >> 1, kh = q & 1;
            meta[16 + off[e] + j] = (e << 16) | (rb << 8) | (cb << 4) | kh;
        }
        int c = counts[e], cp = nt[e] * BM;
        for (int i = c + t; i < cp; i += 256) {
            ltok[e * NTOK + i] = -1;
            lwt[e * NTOK + i]  = 0.f;
        }
    }
}

// ---------------- grouped gathered GEMM: 8-phase counted-vmcnt, K-split-2 ----------------
// R10's verified 256x256 8-phase schedule; each block computes K=512 (kh half),
// NIT=4 iterations. Worklist grid (balanced) + XCD-chunked slot order:
// slot = (bid&7)*80 + bid>>3 with e-major worklist -> XCD k ~ expert k.
__global__ __launch_bounds__(512, 2)
void k_gemm(const unsigned short* __restrict__ xb, const unsigned short* __restrict__ wb,
            const int* __restrict__ ltok, const float* __restrict__ lwt,
            const int* __restrict__ meta, float* __restrict__ out) {
    int T = meta[0];
    int slot = (blockIdx.x & 7) * (MAXT / 8) + (blockIdx.x >> 3);
    if (slot >= T) return;
    int wle = meta[16 + slot];
    int e  = wle >> 16;
    int rb = (wle >> 8) & 255;
    int cb = (wle >> 4) & 15;
    int kh = wle & 15;
    int kB = kh * (NK / 2);           // 0 or 8
    int kE = kB + NK / 2;

    __shared__ unsigned short As[2][BM * BK];   // 2 x 32 KB
    __shared__ unsigned short Bs[2][BN * BK];   // 2 x 32 KB
    __shared__ int   tokS[BM];
    __shared__ float wS[BM];

    int t = threadIdx.x, lane = t & 63, wave = t >> 6;
    int wr = wave >> 2, wc = wave & 3;
    int fr = lane & 15, fq = lane >> 4, fs = fr & 7;
    int pk0 = fq ^ fs, pk1 = (fq + 4) ^ fs;

    if (t < BM) {
        tokS[t] = ltok[e * NTOK + rb * BM + t];
        wS[t]   = lwt[e * NTOK + rb * BM + t];
    }

    // staging sources: 4 rows per thread (j*64 + t>>3), chunk swizzled
    int c0 = t & 7, r0 = t >> 3;
    int csw = c0 ^ (r0 & 7);
    const unsigned short* aS[4];
    const unsigned short* bS[4];
#pragma unroll
    for (int j = 0; j < 4; ++j) {
        int row = j * 64 + r0;
        int tok = ltok[e * NTOK + rb * BM + row];
        int tokc = tok < 0 ? 0 : tok;
        aS[j] = xb + (size_t)tokc * NEMB + csw * 8;
        bS[j] = wb + (size_t)e * NEMB * NEMB + (size_t)(cb * BN + row) * NEMB + csw * 8;
    }
    int off0 = wave * 512;          // elems; HW adds lane*16B
    int off1 = 4096 + wave * 512;

#define GLL(src, dst)                                                                \
    __builtin_amdgcn_global_load_lds(                                                \
        (const __attribute__((address_space(1))) void*)(src),                        \
        (__attribute__((address_space(3))) void*)(dst), 16, 0, 0)
#define STG_A(buf, h, kt) if ((kt) < kE) {                                           \
    GLL(aS[(h)*2 + 0] + (kt)*BK, &As[buf][(h)*8192 + off0]);                         \
    GLL(aS[(h)*2 + 1] + (kt)*BK, &As[buf][(h)*8192 + off1]); }
#define STG_B(buf, h, kt) if ((kt) < kE) {                                           \
    GLL(bS[(h)*2 + 0] + (kt)*BK, &Bs[buf][(h)*8192 + off0]);                         \
    GLL(bS[(h)*2 + 1] + (kt)*BK, &Bs[buf][(h)*8192 + off1]); }

#define LDA(mh, buf) { _Pragma("unroll")                                             \
    for (int m = 0; m < 4; ++m) {                                                    \
        int row = ((mh)*4 + m)*32 + wr*16 + fr;                                      \
        af[m][0] = *reinterpret_cast<const bf16x8*>(&As[buf][row*BK + pk0*8]);       \
        af[m][1] = *reinterpret_cast<const bf16x8*>(&As[buf][row*BK + pk1*8]); } }
#define LDB(dst, nh, buf) { _Pragma("unroll")                                        \
    for (int n = 0; n < 2; ++n) {                                                    \
        int row = ((nh)*2 + n)*64 + wc*16 + fr;                                      \
        dst[n][0] = *reinterpret_cast<const bf16x8*>(&Bs[buf][row*BK + pk0*8]);      \
        dst[n][1] = *reinterpret_cast<const bf16x8*>(&Bs[buf][row*BK + pk1*8]); } }
#define MM(mh, nh, bfx) { _Pragma("unroll")                                          \
    for (int m = 0; m < 4; ++m) { _Pragma("unroll")                                  \
        for (int n = 0; n < 2; ++n) {                                                \
            acc[(mh)*4+m][(nh)*2+n] = __builtin_amdgcn_mfma_f32_16x16x32_bf16(       \
                af[m][0], bfx[n][0], acc[(mh)*4+m][(nh)*2+n], 0, 0, 0);              \
            acc[(mh)*4+m][(nh)*2+n] = __builtin_amdgcn_mfma_f32_16x16x32_bf16(       \
                af[m][1], bfx[n][1], acc[(mh)*4+m][(nh)*2+n], 0, 0, 0); } } }
#define BAR   __builtin_amdgcn_s_barrier()
#define LGKM0 asm volatile("s_waitcnt lgkmcnt(0)" ::: "memory")
#define VM6   asm volatile("s_waitcnt vmcnt(6)" ::: "memory")
#define VM0   asm volatile("s_waitcnt vmcnt(0)" ::: "memory")
#define PRI1  __builtin_amdgcn_s_setprio(1)
#define PRI0  __builtin_amdgcn_s_setprio(0)

    f32x4 acc[8][4];
#pragma unroll
    for (int m = 0; m < 8; ++m)
#pragma unroll
        for (int n = 0; n < 4; ++n) acc[m][n] = (f32x4){0.f, 0.f, 0.f, 0.f};

    bf16x8 af[4][2], bf0[2][2], bf1[2][2];

    // prologue: K(kB) full + K(kB+1) {Ah0,Bh0,Bh1}
    STG_A(0, 0, kB); STG_B(0, 0, kB); STG_A(0, 1, kB); STG_B(0, 1, kB);
    STG_A(1, 0, kB + 1); STG_B(1, 0, kB + 1); STG_B(1, 1, kB + 1);
    VM6; LGKM0; BAR;    // kB's 4 halves (oldest 8 loads) landed; tokS visible

    for (int i = 0; i < 4; ++i) {
        int kt1 = kB + 2 * i + 1;
        int n0  = kB + 2 * i + 2;
        int n1  = kB + 2 * i + 3;
        bool lastIt = (i == 3);

        // ---- P1: read mh0+nh0 of buf0; stage Ah1(kt1) ----
        LDA(0, 0); LDB(bf0, 0, 0);
        STG_A(1, 1, kt1);
        BAR; LGKM0; PRI1; MM(0, 0, bf0); PRI0; BAR;
        // ---- P2: read nh1 of buf0; stage Ah0(n0) ----
        LDB(bf1, 1, 0);
        STG_A(0, 0, n0);
        BAR; LGKM0; PRI1; MM(0, 1, bf1); PRI0; BAR;
        // ---- P3: read mh1 of buf0; stage Bh0(n0) ----
        LDA(1, 0);
        STG_B(0, 0, n0);
        BAR; LGKM0; PRI1; MM(1, 0, bf0); PRI0; BAR;
        // ---- P4: stage Ah1(n0); counted wait ----
        STG_A(0, 1, n0);
        if (lastIt) { VM0; } else { VM6; }
        BAR; PRI1; MM(1, 1, bf1); PRI0; BAR;
        // ---- P5: read mh0+nh0 of buf1; stage Bh1(n0) ----
        LDA(0, 1); LDB(bf0, 0, 1);
        STG_B(0, 1, n0);
        BAR; LGKM0; PRI1; MM(0, 0, bf0); PRI0; BAR;
        // ---- P6: read nh1 of buf1; stage Ah0(n1) ----
        LDB(bf1, 1, 1);
        STG_A(1, 0, n1);
        BAR; LGKM0; PRI1; MM(0, 1, bf1); PRI0; BAR;
        // ---- P7: read mh1 of buf1; stage Bh0(n1) ----
        LDA(1, 1);
        STG_B(1, 0, n1);
        BAR; LGKM0; PRI1; MM(1, 0, bf0); PRI0; BAR;
        // ---- P8: stage Bh1(n1); counted wait ----
        STG_B(1, 1, n1);
        if (!lastIt) { VM6; }
        BAR; PRI1; MM(1, 1, bf1); PRI0; BAR;
    }

#undef GLL
#undef STG_A
#undef STG_B
#undef LDA
#undef LDB
#undef MM

    // epilogue: weighted atomic scatter (each out element receives <= 4 adds)
#pragma unroll
    for (int m = 0; m < 8; ++m) {
#pragma unroll
        for (int jj = 0; jj < 4; ++jj) {
            int row = m * 32 + wr * 16 + fq * 4 + jj;
            int tok = tokS[row];
            if (tok < 0) continue;
            float wgt = wS[row];
            float* orow = out + (size_t)tok * NEMB + cb * BN + wc * 16 + fr;
#pragma unroll
            for (int n = 0; n < 4; ++n)
                unsafeAtomicAdd(orow + n * 64, wgt * acc[m][n][jj]);
        }
    }
}

extern "C" void kernel_launch(void* const* d_in, const int* in_sizes, int n_in,
                              void* d_out, int out_size, void* d_ws, size_t ws_size,
                              hipStream_t stream) {
    const float* x  = (const float*)d_in[0];
    const float* gw = (const float*)d_in[1];
    const float* ew = (const float*)d_in[2];
    float* out = (float*)d_out;

    char* ws = (char*)d_ws;
    unsigned short* xb = (unsigned short*)(ws);
    unsigned short* wb = (unsigned short*)(ws + XB_BYTES);
    int*   counts = (int*)(ws + CNT_OFF);
    int*   ltok   = (int*)(ws + LTOK_OFF);
    float* lwt    = (float*)(ws + LWT_OFF);
    int4*  selw   = (int4*)(ws + SELW_OFF);
    int*   meta   = (int*)(ws + META_OFF);

    hipMemsetAsync(counts, 0, 8 * sizeof(int), stream);
    hipMemsetAsync(out, 0, (size_t)NTOK * NEMB * sizeof(float), stream);

    // fused cvt + gate: 4096 cvt blocks + 2048 gate blocks
    k_prep<<<4096 + NTOK / 4, 256, 0, stream>>>(x, gw, ew, wb, xb, selw);
    k_build<<<dim3(NTOK / BLD_STRIPE, NEXP), 256, 0, stream>>>(selw, counts, ltok, lwt);
    k_padW<<<1, 256, 0, stream>>>(counts, ltok, lwt, meta);
    // worklist grid: MAXT slots, XCD-chunked slot order; idle slots exit on meta[0]
    k_gemm<<<MAXT, 512, 0, stream>>>(xb, wb, ltok, lwt, meta, out);
}